// Round 3
// baseline (1267.140 us; speedup 1.0000x reference)
//
#include <hip/hip_runtime.h>
#include <hip/hip_bf16.h>

// MicroContinuumCell — MI355X. f32 I/O; bf16 MFMA internally.
// Workspace layout (~203 MB):
//   [0)            v bf16  [N][256]           134217728 B
//   [134217728)    sigmoid(gate_raw) f32 [N]    1048576 B
//   [135266304)    scal f32[64]: 0=|W|^2, 1=sum_c0, 2=sum_c2, 3=|mem|^2
//   [135266560)    colv2 f32[256]
//   [135267584)    mem f32[65536]
//   [135529728)    hebb partials f32[256][65536] 67108864 B
//   [202638592)    Vb bf16[65536]  131072 B
//   [202769664)    Wb bf16[65536]  131072 B

#define NTOK 262144

typedef short s16x4 __attribute__((ext_vector_type(4)));
typedef short s16x8 __attribute__((ext_vector_type(8)));
typedef float f32x4 __attribute__((ext_vector_type(4)));
typedef unsigned int u32x4 __attribute__((ext_vector_type(4)));
typedef __bf16 bf16x8 __attribute__((ext_vector_type(8)));

static __device__ __forceinline__ float b2f(short s) {
  unsigned int u = ((unsigned int)(unsigned short)s) << 16;
  return __builtin_bit_cast(float, u);
}
static __device__ __forceinline__ short f2b(float f) {
  __hip_bfloat16 h = __float2bfloat16(f);
  return (short)__builtin_bit_cast(unsigned short, h);
}
static __device__ __forceinline__ float clip2(float f) {
  return fminf(2.f, fmaxf(-2.f, f));
}
static __device__ __forceinline__ unsigned int packu(short lo, short hi) {
  return (unsigned int)(unsigned short)lo | ((unsigned int)(unsigned short)hi << 16);
}
static __device__ __forceinline__ f32x4 mfma16(s16x8 a, s16x8 b, f32x4 c) {
  return __builtin_amdgcn_mfma_f32_16x16x32_bf16(
      __builtin_bit_cast(bf16x8, a), __builtin_bit_cast(bf16x8, b), c, 0, 0, 0);
}

// ---------------------------------------------------------------- k_prep
// 16 blocks x 1024: convert V,W -> bf16 (Vb,Wb) and accumulate |W|^2 into
// scal[0] (pre-zeroed by hipMemsetAsync).
__global__ __launch_bounds__(1024) void k_prep(const float* __restrict__ V,
                                               const float* __restrict__ W,
                                               short* __restrict__ Vb,
                                               short* __restrict__ Wb,
                                               float* __restrict__ scal) {
  int t = blockIdx.x * 1024 + threadIdx.x;  // 16384 threads, 4 elems each
  f32x4 v4 = *(const f32x4*)(V + (size_t)t * 4);
  f32x4 w4 = *(const f32x4*)(W + (size_t)t * 4);
  s16x4 vb, wb;
  float s = 0.f;
#pragma unroll
  for (int e = 0; e < 4; ++e) {
    vb[e] = f2b(v4[e]);
    wb[e] = f2b(w4[e]);
    s += w4[e] * w4[e];
  }
  *(s16x4*)(Vb + (size_t)t * 4) = vb;
  *(s16x4*)(Wb + (size_t)t * 4) = wb;
#pragma unroll
  for (int d = 1; d < 64; d <<= 1) s += __shfl_xor(s, d);
  __shared__ float r[16];
  if ((threadIdx.x & 63) == 0) r[threadIdx.x >> 6] = s;
  __syncthreads();
  if (threadIdx.x == 0) {
    float tt = 0.f;
#pragma unroll
    for (int i = 0; i < 16; ++i) tt += r[i];
    atomicAdd(&scal[0], tt);
  }
}

// ---------------------------------------------------------------- k_main
// Per block: 128 rows of x, fused v = clip(x V^T) and h = x W^T.
// 8 waves (2x4), BK=32, 2-phase register-prefetch pipeline:
//   write LDS(ks); barrier; load regs(ks+1); ds_read+MFMA(ks); barrier.
__global__ __launch_bounds__(512, 4) void k_main(
    const float* __restrict__ x, const short* __restrict__ Vb,
    const short* __restrict__ Wb, const float* __restrict__ gw,
    const float* __restrict__ gb, const float* __restrict__ s1w,
    const float* __restrict__ s1b, const float* __restrict__ lng,
    const float* __restrict__ lnb, const float* __restrict__ s2w,
    const float* __restrict__ s2b, const float* __restrict__ aw,
    const float* __restrict__ ab, short* __restrict__ v_out,
    float* __restrict__ g_out, float* __restrict__ scal) {
  __shared__ __align__(16) short lds[128 * 40 + 2 * 256 * 40];  // 50 KiB
  short* xs = lds;
  short* vs = lds + 128 * 40;
  short* ws2 = vs + 256 * 40;
  int tid = threadIdx.x;
  int lane = tid & 63, wid = tid >> 6;
  int lr = lane & 15, lg = lane >> 4;
  int wr = wid >> 2, wc = wid & 3;
  size_t r0 = (size_t)blockIdx.x * 128;

  f32x4 accv[4][4] = {};
  f32x4 acch[4][4] = {};
  float sx = 0.f, sxx = 0.f;

  // staging geometry
  int srow = tid >> 2, skc = tid & 3;                 // x: row 0..127, 8-col chunk
  int vrow0 = tid >> 2, vkc0 = tid & 3;               // V/W pass 0: rows 0..127
  int vrow1 = 128 + (tid >> 2), vkc1 = tid & 3;       // V/W pass 1: rows 128..255

  // prefetch registers
  f32x4 rxa, rxb;
  s16x8 rv0, rv1, rw0, rw1;

  // prologue: load ks=0
  {
    const float* src = x + (r0 + srow) * 256 + skc * 8;
    rxa = *(const f32x4*)(src);
    rxb = *(const f32x4*)(src + 4);
    rv0 = *(const s16x8*)(Vb + (size_t)vrow0 * 256 + vkc0 * 8);
    rv1 = *(const s16x8*)(Vb + (size_t)vrow1 * 256 + vkc1 * 8);
    rw0 = *(const s16x8*)(Wb + (size_t)vrow0 * 256 + vkc0 * 8);
    rw1 = *(const s16x8*)(Wb + (size_t)vrow1 * 256 + vkc1 * 8);
  }

  for (int ks = 0; ks < 8; ++ks) {
    // ---- write staged registers to LDS (+ row stats from f32 regs)
    {
      s16x8 c;
#pragma unroll
      for (int e = 0; e < 4; ++e) {
        float f0 = rxa[e], f1 = rxb[e];
        sx += f0 + f1;
        sxx += f0 * f0 + f1 * f1;
        c[e] = f2b(f0);
        c[4 + e] = f2b(f1);
      }
      *(s16x8*)(xs + srow * 40 + skc * 8) = c;
      *(s16x8*)(vs + vrow0 * 40 + vkc0 * 8) = rv0;
      *(s16x8*)(vs + vrow1 * 40 + vkc1 * 8) = rv1;
      *(s16x8*)(ws2 + vrow0 * 40 + vkc0 * 8) = rw0;
      *(s16x8*)(ws2 + vrow1 * 40 + vkc1 * 8) = rw1;
    }
    __syncthreads();
    // ---- issue next K-step's global loads (latency hides under MFMA)
    if (ks < 7) {
      int k0 = (ks + 1) * 32;
      const float* src = x + (r0 + srow) * 256 + k0 + skc * 8;
      rxa = *(const f32x4*)(src);
      rxb = *(const f32x4*)(src + 4);
      rv0 = *(const s16x8*)(Vb + (size_t)vrow0 * 256 + k0 + vkc0 * 8);
      rv1 = *(const s16x8*)(Vb + (size_t)vrow1 * 256 + k0 + vkc1 * 8);
      rw0 = *(const s16x8*)(Wb + (size_t)vrow0 * 256 + k0 + vkc0 * 8);
      rw1 = *(const s16x8*)(Wb + (size_t)vrow1 * 256 + k0 + vkc1 * 8);
    }
    // ---- fragments + MFMA
    s16x8 bv[4], bw[4];
#pragma unroll
    for (int nf = 0; nf < 4; ++nf) {
      bv[nf] = *(const s16x8*)(vs + (wc * 64 + nf * 16 + lr) * 40 + lg * 8);
      bw[nf] = *(const s16x8*)(ws2 + (wc * 64 + nf * 16 + lr) * 40 + lg * 8);
    }
#pragma unroll
    for (int mf = 0; mf < 4; ++mf) {
      s16x8 a = *(const s16x8*)(xs + (wr * 64 + mf * 16 + lr) * 40 + lg * 8);
#pragma unroll
      for (int nf = 0; nf < 4; ++nf) {
        accv[mf][nf] = mfma16(a, bv[nf], accv[mf][nf]);
        acch[mf][nf] = mfma16(a, bw[nf], acch[mf][nf]);
      }
    }
    __syncthreads();
  }

  // clip v; per-lane partials: gate dot and sum|h| per output row
  float gw4[4];
#pragma unroll
  for (int nf = 0; nf < 4; ++nf) gw4[nf] = gw[wc * 64 + nf * 16 + lr];
  float gd[4][4], hb[4][4];
#pragma unroll
  for (int mf = 0; mf < 4; ++mf)
#pragma unroll
    for (int e = 0; e < 4; ++e) { gd[mf][e] = 0.f; hb[mf][e] = 0.f; }
#pragma unroll
  for (int mf = 0; mf < 4; ++mf)
#pragma unroll
    for (int nf = 0; nf < 4; ++nf)
#pragma unroll
      for (int e = 0; e < 4; ++e) {
        float v = clip2(accv[mf][nf][e]);
        accv[mf][nf][e] = v;
        gd[mf][e] += v * gw4[nf];
        hb[mf][e] += fabsf(acch[mf][nf][e]);
      }
  // butterfly over the 16-col lane group (C/D: col = lane&15)
#pragma unroll
  for (int d = 1; d < 16; d <<= 1)
#pragma unroll
    for (int mf = 0; mf < 4; ++mf)
#pragma unroll
      for (int e = 0; e < 4; ++e) {
        gd[mf][e] += __shfl_xor(gd[mf][e], d);
        hb[mf][e] += __shfl_xor(hb[mf][e], d);
      }
  // row-stat reduce over the 4 threads sharing a row (skc 0..3)
  sx += __shfl_xor(sx, 1); sx += __shfl_xor(sx, 2);
  sxx += __shfl_xor(sxx, 1); sxx += __shfl_xor(sxx, 2);

  __syncthreads();
  float* red = (float*)lds;  // [0)=gate dot,[128)=|h| sum,[256)=sx,[384)=sxx
  if (tid < 256) red[tid] = 0.f;
  __syncthreads();
  if (lr == 0) {
#pragma unroll
    for (int mf = 0; mf < 4; ++mf)
#pragma unroll
      for (int e = 0; e < 4; ++e) {
        int row = wr * 64 + mf * 16 + lg * 4 + e;
        atomicAdd(&red[row], gd[mf][e]);
        atomicAdd(&red[128 + row], hb[mf][e]);
      }
  }
  if (skc == 0) { red[256 + srow] = sx; red[384 + srow] = sxx; }
  // store clipped v (bf16)
#pragma unroll
  for (int mf = 0; mf < 4; ++mf)
#pragma unroll
    for (int nf = 0; nf < 4; ++nf)
#pragma unroll
      for (int e = 0; e < 4; ++e) {
        int row = wr * 64 + mf * 16 + lg * 4 + e;
        int col = wc * 64 + nf * 16 + lr;
        v_out[(r0 + row) * 256 + col] = f2b(accv[mf][nf][e]);
      }
  __syncthreads();

  // homeostatic MLP: one thread per row (threads 0..127)
  float c0v = 0.f, c2v = 0.f;
  if (tid < 128) {
    int row = tid;
    float mean = red[256 + row] * (1.f / 256.f);
    float var = red[384 + row] * (1.f / 256.f) - mean * mean;
    float st[4];
    st[0] = fabsf(var - 0.5f);               // surprise
    st[1] = red[128 + row] * (1.f / 256.f);  // excitation
    st[2] = sqrtf(scal[0]);                  // fatigue = |W|_F
    st[3] = 0.5f;                            // coherence
    float z[16];
#pragma unroll
    for (int o = 0; o < 16; ++o) {
      float a = s1b[o];
#pragma unroll
      for (int i = 0; i < 4; ++i) a += s1w[o * 4 + i] * st[i];
      z[o] = a;
    }
    float mu = 0.f;
#pragma unroll
    for (int o = 0; o < 16; ++o) mu += z[o];
    mu *= (1.f / 16.f);
    float vz = 0.f;
#pragma unroll
    for (int o = 0; o < 16; ++o) { float d2 = z[o] - mu; vz += d2 * d2; }
    vz *= (1.f / 16.f);
    float rs = rsqrtf(vz + 1e-5f);
#pragma unroll
    for (int o = 0; o < 16; ++o)
      z[o] = tanhf((z[o] - mu) * rs * lng[o] + lnb[o]);
    float z2[8];
#pragma unroll
    for (int o = 0; o < 8; ++o) {
      float a = s2b[o];
#pragma unroll
      for (int i = 0; i < 16; ++i) a += s2w[o * 16 + i] * z[i];
      z2[o] = fmaxf(a, 0.f);
    }
    float cc[2];
#pragma unroll
    for (int q = 0; q < 2; ++q) {
      int o = q * 2;  // controls[0] and controls[2]
      float a = ab[o];
#pragma unroll
      for (int i = 0; i < 8; ++i) a += aw[o * 8 + i] * z2[i];
      cc[q] = 1.f / (1.f + expf(-a));
    }
    c0v = cc[0]; c2v = cc[1];
    float graw = red[row] + gb[0];
    g_out[r0 + row] = 1.f / (1.f + expf(-graw));
  }
#pragma unroll
  for (int d = 1; d < 64; d <<= 1) {
    c0v += __shfl_xor(c0v, d);
    c2v += __shfl_xor(c2v, d);
  }
  if (lane == 0 && wid < 2) {
    atomicAdd(&scal[1], c0v);
    atomicAdd(&scal[2], c2v);
  }
}

// ---------------------------------------------------------------- k_hebb
// Split-K v^T x (K = 1024 rows per block) + fused output-0 write + col sum v^2.
__global__ __launch_bounds__(512, 2) void k_hebb(
    const float* __restrict__ x, const short* __restrict__ v_in,
    const float* __restrict__ g_sig, const float* __restrict__ scal,
    float* __restrict__ colv2, float* __restrict__ parts,
    float* __restrict__ out0) {
  __shared__ __align__(16) unsigned int ldsT[2 * 256 * 17];  // 34 KiB
  unsigned int* vT = ldsT;
  unsigned int* xT = ldsT + 256 * 17;
  int tid = threadIdx.x;
  int lane = tid & 63, wid = tid >> 6;
  int lr = lane & 15, lg = lane >> 4;
  int wr = wid >> 2, wc = wid & 3;
  size_t n0 = (size_t)blockIdx.x * 1024;
  float gv = scal[2] * (1.f / 262144.f);  // gate_value

  f32x4 acc[8][4] = {};
  float cv2[8] = {0.f, 0.f, 0.f, 0.f, 0.f, 0.f, 0.f, 0.f};
  int np = tid >> 5, ic = tid & 31, i0 = ic * 8;

  for (int nt = 0; nt < 32; ++nt) {
    size_t nr = n0 + nt * 32 + np * 2;
    s16x8 va = *(const s16x8*)(v_in + nr * 256 + i0);
    s16x8 vb = *(const s16x8*)(v_in + (nr + 1) * 256 + i0);
    f32x4 xa0 = *(const f32x4*)(x + nr * 256 + i0);
    f32x4 xa1 = *(const f32x4*)(x + nr * 256 + i0 + 4);
    f32x4 xb0 = *(const f32x4*)(x + (nr + 1) * 256 + i0);
    f32x4 xb1 = *(const f32x4*)(x + (nr + 1) * 256 + i0 + 4);
    float sa = g_sig[nr] * gv, sb = g_sig[nr + 1] * gv;
    f32x4 oa0, oa1, ob0, ob1;
#pragma unroll
    for (int j = 0; j < 4; ++j) {
      float fa = b2f(va[j]), fA = b2f(va[4 + j]);
      float fb = b2f(vb[j]), fB = b2f(vb[4 + j]);
      cv2[j] += fa * fa + fb * fb;
      cv2[4 + j] += fA * fA + fB * fB;
      oa0[j] = clip2(fa * sa); oa1[j] = clip2(fA * sa);
      ob0[j] = clip2(fb * sb); ob1[j] = clip2(fB * sb);
      vT[(i0 + j) * 17 + np] = packu(va[j], vb[j]);
      vT[(i0 + 4 + j) * 17 + np] = packu(va[4 + j], vb[4 + j]);
      xT[(i0 + j) * 17 + np] = packu(f2b(xa0[j]), f2b(xb0[j]));
      xT[(i0 + 4 + j) * 17 + np] = packu(f2b(xa1[j]), f2b(xb1[j]));
    }
    *(f32x4*)(out0 + nr * 256 + i0) = oa0;
    *(f32x4*)(out0 + nr * 256 + i0 + 4) = oa1;
    *(f32x4*)(out0 + (nr + 1) * 256 + i0) = ob0;
    *(f32x4*)(out0 + (nr + 1) * 256 + i0 + 4) = ob1;
    __syncthreads();
    int npb = lg * 4;
    s16x8 bfr[4];
#pragma unroll
    for (int nf = 0; nf < 4; ++nf) {
      int j = wc * 64 + nf * 16 + lr;
      u32x4 q;
      q[0] = xT[j * 17 + npb]; q[1] = xT[j * 17 + npb + 1];
      q[2] = xT[j * 17 + npb + 2]; q[3] = xT[j * 17 + npb + 3];
      bfr[nf] = __builtin_bit_cast(s16x8, q);
    }
#pragma unroll
    for (int mf = 0; mf < 8; ++mf) {
      int i = wr * 128 + mf * 16 + lr;
      u32x4 q;
      q[0] = vT[i * 17 + npb]; q[1] = vT[i * 17 + npb + 1];
      q[2] = vT[i * 17 + npb + 2]; q[3] = vT[i * 17 + npb + 3];
      s16x8 afr = __builtin_bit_cast(s16x8, q);
#pragma unroll
      for (int nf = 0; nf < 4; ++nf)
        acc[mf][nf] = mfma16(afr, bfr[nf], acc[mf][nf]);
    }
    __syncthreads();
  }
  float* myp = parts + (size_t)blockIdx.x * 65536;
#pragma unroll
  for (int mf = 0; mf < 8; ++mf)
#pragma unroll
    for (int nf = 0; nf < 4; ++nf)
#pragma unroll
      for (int e = 0; e < 4; ++e) {
        int i = wr * 128 + mf * 16 + lg * 4 + e;
        int j = wc * 64 + nf * 16 + lr;
        myp[i * 256 + j] = acc[mf][nf][e];
      }
  __syncthreads();
  float* cred = (float*)ldsT;
  if (tid < 256) cred[tid] = 0.f;
  __syncthreads();
#pragma unroll
  for (int j = 0; j < 8; ++j) atomicAdd(&cred[i0 + j], cv2[j]);
  __syncthreads();
  if (tid < 256) atomicAdd(&colv2[tid], cred[tid]);
}

// ---------------------------------------------------------------- k_mem1/2
__global__ __launch_bounds__(256) void k_mem1(
    const float* __restrict__ parts, const float* __restrict__ colv2,
    const float* __restrict__ sm, float* __restrict__ mem,
    float* __restrict__ scal) {
  int i = blockIdx.x, j = threadIdx.x;
  float hebb = 0.f;
#pragma unroll 8
  for (int p = 0; p < 256; ++p) hebb += parts[(size_t)p * 65536 + i * 256 + j];
  hebb *= (1.f / 262144.f);
  float mr = scal[1] * (1.f / 262144.f);  // metabolic_rate
  float smv = sm[i * 256 + j];
  float forget = colv2[i] * (1.f / 262144.f) * smv;
  float delta = tanhf(hebb - forget);
  float m = smv + delta * mr * 0.1f;
  mem[i * 256 + j] = m;
  float s = m * m;
#pragma unroll
  for (int d = 1; d < 64; d <<= 1) s += __shfl_xor(s, d);
  __shared__ float r4[4];
  if ((j & 63) == 0) r4[j >> 6] = s;
  __syncthreads();
  if (j == 0) atomicAdd(&scal[3], r4[0] + r4[1] + r4[2] + r4[3]);
}

__global__ __launch_bounds__(256) void k_mem2(const float* __restrict__ mem,
                                              const float* __restrict__ scal,
                                              float* __restrict__ out1) {
  int idx = blockIdx.x * 256 + threadIdx.x;
  float scale = 0.5f / fmaxf(sqrtf(scal[3]), 1e-6f);
  out1[idx] = mem[idx] * scale;
}

// ---------------------------------------------------------------- launch
extern "C" void kernel_launch(void* const* d_in, const int* in_sizes, int n_in,
                              void* d_out, int out_size, void* d_ws, size_t ws_size,
                              hipStream_t stream) {
  (void)in_sizes; (void)n_in; (void)out_size; (void)ws_size;
  const float* x   = (const float*)d_in[0];
  const float* Wm  = (const float*)d_in[1];
  const float* Vm  = (const float*)d_in[2];
  const float* gw  = (const float*)d_in[3];
  const float* gb  = (const float*)d_in[4];
  const float* s1w = (const float*)d_in[5];
  const float* s1b = (const float*)d_in[6];
  const float* lng = (const float*)d_in[7];
  const float* lnb = (const float*)d_in[8];
  const float* s2w = (const float*)d_in[9];
  const float* s2b = (const float*)d_in[10];
  const float* aw  = (const float*)d_in[11];
  const float* ab  = (const float*)d_in[12];
  const float* sm  = (const float*)d_in[13];
  float* out0 = (float*)d_out;
  float* out1 = out0 + (size_t)NTOK * 256;

  char* w = (char*)d_ws;
  short* v_ws  = (short*)w;                    // 134217728
  float* g_ws  = (float*)(w + 134217728);      // 1048576
  float* scal  = (float*)(w + 135266304);      // 256
  float* colv2 = (float*)(w + 135266560);      // 1024
  float* mem   = (float*)(w + 135267584);      // 262144
  float* parts = (float*)(w + 135529728);      // 67108864
  short* Vb    = (short*)(w + 202638592);      // 131072
  short* Wb    = (short*)(w + 202769664);      // 131072 (end ~202.9 MB)

  hipMemsetAsync(scal, 0, 1280, stream);       // scal[64] + colv2[256]
  k_prep<<<16, 1024, 0, stream>>>(Vm, Wm, Vb, Wb, scal);
  k_main<<<2048, 512, 0, stream>>>(x, Vb, Wb, gw, gb, s1w, s1b, lng, lnb,
                                   s2w, s2b, aw, ab, v_ws, g_ws, scal);
  k_hebb<<<256, 512, 0, stream>>>(x, v_ws, g_ws, scal, colv2, parts, out0);
  k_mem1<<<256, 256, 0, stream>>>(parts, colv2, sm, mem, scal);
  k_mem2<<<256, 256, 0, stream>>>(mem, scal, out1);
}

// Round 4
// 506.251 us; speedup vs baseline: 2.5030x; 2.5030x over previous
//
#include <hip/hip_runtime.h>
#include <hip/hip_bf16.h>

// MicroContinuumCell — MI355X. f32 I/O; bf16 MFMA internally.
// k_main is LDS-free in the main loop: A (x) and B (Vb/Wb) fragments are
// loaded directly from global in MFMA fragment layout (B is 256 KB,
// L2-resident, shared by all blocks). No barriers until the epilogue.
// Workspace layout (~203 MB):
//   [0)            v bf16  [N][256]           134217728 B
//   [134217728)    sigmoid(gate_raw) f32 [N]    1048576 B
//   [135266304)    scal f32[64]: 0=|W|^2, 1=sum_c0, 2=sum_c2, 3=|mem|^2
//   [135266560)    colv2 f32[256]
//   [135267584)    mem f32[65536]
//   [135529728)    hebb partials f32[256][65536] 67108864 B
//   [202638592)    Vb bf16[65536]  131072 B
//   [202769664)    Wb bf16[65536]  131072 B

#define NTOK 262144

typedef short s16x4 __attribute__((ext_vector_type(4)));
typedef short s16x8 __attribute__((ext_vector_type(8)));
typedef float f32x4 __attribute__((ext_vector_type(4)));
typedef unsigned int u32x4 __attribute__((ext_vector_type(4)));
typedef __bf16 bf16x8 __attribute__((ext_vector_type(8)));

static __device__ __forceinline__ float b2f(short s) {
  unsigned int u = ((unsigned int)(unsigned short)s) << 16;
  return __builtin_bit_cast(float, u);
}
static __device__ __forceinline__ short f2b(float f) {
  __hip_bfloat16 h = __float2bfloat16(f);
  return (short)__builtin_bit_cast(unsigned short, h);
}
static __device__ __forceinline__ float clip2(float f) {
  return fminf(2.f, fmaxf(-2.f, f));
}
static __device__ __forceinline__ unsigned int packu(short lo, short hi) {
  return (unsigned int)(unsigned short)lo | ((unsigned int)(unsigned short)hi << 16);
}
static __device__ __forceinline__ f32x4 mfma16(s16x8 a, s16x8 b, f32x4 c) {
  return __builtin_amdgcn_mfma_f32_16x16x32_bf16(
      __builtin_bit_cast(bf16x8, a), __builtin_bit_cast(bf16x8, b), c, 0, 0, 0);
}

// ---------------------------------------------------------------- k_prep
// 16 blocks x 1024: convert V,W -> bf16 (Vb,Wb) and accumulate |W|^2 into
// scal[0] (pre-zeroed by hipMemsetAsync).
__global__ __launch_bounds__(1024) void k_prep(const float* __restrict__ V,
                                               const float* __restrict__ W,
                                               short* __restrict__ Vb,
                                               short* __restrict__ Wb,
                                               float* __restrict__ scal) {
  int t = blockIdx.x * 1024 + threadIdx.x;  // 16384 threads, 4 elems each
  f32x4 v4 = *(const f32x4*)(V + (size_t)t * 4);
  f32x4 w4 = *(const f32x4*)(W + (size_t)t * 4);
  s16x4 vb, wb;
  float s = 0.f;
#pragma unroll
  for (int e = 0; e < 4; ++e) {
    vb[e] = f2b(v4[e]);
    wb[e] = f2b(w4[e]);
    s += w4[e] * w4[e];
  }
  *(s16x4*)(Vb + (size_t)t * 4) = vb;
  *(s16x4*)(Wb + (size_t)t * 4) = wb;
#pragma unroll
  for (int d = 1; d < 64; d <<= 1) s += __shfl_xor(s, d);
  __shared__ float r[16];
  if ((threadIdx.x & 63) == 0) r[threadIdx.x >> 6] = s;
  __syncthreads();
  if (threadIdx.x == 0) {
    float tt = 0.f;
#pragma unroll
    for (int i = 0; i < 16; ++i) tt += r[i];
    atomicAdd(&scal[0], tt);
  }
}

// ---------------------------------------------------------------- k_main
// Per block: 128 rows of x, fused v = clip(x V^T) and h = x W^T.
// 8 waves (2 M x 4 N), each owns a 64x64 output tile of BOTH products.
// Operands loaded straight from global in fragment layout; no main-loop
// LDS, no main-loop barriers.
__global__ __launch_bounds__(512, 2) void k_main(
    const float* __restrict__ x, const short* __restrict__ Vb,
    const short* __restrict__ Wb, const float* __restrict__ gw,
    const float* __restrict__ gb, const float* __restrict__ s1w,
    const float* __restrict__ s1b, const float* __restrict__ lng,
    const float* __restrict__ lnb, const float* __restrict__ s2w,
    const float* __restrict__ s2b, const float* __restrict__ aw,
    const float* __restrict__ ab, short* __restrict__ v_out,
    float* __restrict__ g_out, float* __restrict__ scal) {
  __shared__ float red[512];  // [0)=gate dot,[128)=|h|,[256)=sx,[384)=sxx
  int tid = threadIdx.x;
  int lane = tid & 63, wid = tid >> 6;
  int lr = lane & 15, lg = lane >> 4;
  int wr = wid >> 2, wc = wid & 3;
  size_t r0 = (size_t)blockIdx.x * 128;

  f32x4 accv[4][4] = {};
  f32x4 acch[4][4] = {};
  float sx[4] = {0.f, 0.f, 0.f, 0.f};
  float sxx[4] = {0.f, 0.f, 0.f, 0.f};

  const short* vbase = Vb + (size_t)(wc * 64 + lr) * 256 + lg * 8;
  const short* wbase = Wb + (size_t)(wc * 64 + lr) * 256 + lg * 8;
  const float* xbase = x + (r0 + wr * 64 + lr) * 256 + lg * 8;

#pragma unroll 2
  for (int ks = 0; ks < 8; ++ks) {
    int k0 = ks * 32;
    s16x8 bv[4], bw[4];
#pragma unroll
    for (int nf = 0; nf < 4; ++nf) {
      bv[nf] = *(const s16x8*)(vbase + nf * 16 * 256 + k0);
      bw[nf] = *(const s16x8*)(wbase + nf * 16 * 256 + k0);
    }
#pragma unroll
    for (int mf = 0; mf < 4; ++mf) {
      const float* ap = xbase + mf * 16 * 256 + k0;
      f32x4 a0 = *(const f32x4*)(ap);
      f32x4 a1 = *(const f32x4*)(ap + 4);
      s16x8 a;
#pragma unroll
      for (int e = 0; e < 4; ++e) { a[e] = f2b(a0[e]); a[4 + e] = f2b(a1[e]); }
      if (wc == 0) {  // wave-uniform: stats only on the wc==0 waves
#pragma unroll
        for (int e = 0; e < 4; ++e) {
          sx[mf] += a0[e] + a1[e];
          sxx[mf] += a0[e] * a0[e] + a1[e] * a1[e];
        }
      }
#pragma unroll
      for (int nf = 0; nf < 4; ++nf) {
        accv[mf][nf] = mfma16(a, bv[nf], accv[mf][nf]);
        acch[mf][nf] = mfma16(a, bw[nf], acch[mf][nf]);
      }
    }
  }

  // clip v; per-lane partials: gate dot and sum|h| per output row
  float gw4[4];
#pragma unroll
  for (int nf = 0; nf < 4; ++nf) gw4[nf] = gw[wc * 64 + nf * 16 + lr];
  float gd[4][4], hb[4][4];
#pragma unroll
  for (int mf = 0; mf < 4; ++mf)
#pragma unroll
    for (int e = 0; e < 4; ++e) { gd[mf][e] = 0.f; hb[mf][e] = 0.f; }
#pragma unroll
  for (int mf = 0; mf < 4; ++mf)
#pragma unroll
    for (int nf = 0; nf < 4; ++nf)
#pragma unroll
      for (int e = 0; e < 4; ++e) {
        float v = clip2(accv[mf][nf][e]);
        accv[mf][nf][e] = v;
        gd[mf][e] += v * gw4[nf];
        hb[mf][e] += fabsf(acch[mf][nf][e]);
      }
  // butterfly over the 16-col lane group (C/D: col = lane&15)
#pragma unroll
  for (int d = 1; d < 16; d <<= 1)
#pragma unroll
    for (int mf = 0; mf < 4; ++mf)
#pragma unroll
      for (int e = 0; e < 4; ++e) {
        gd[mf][e] += __shfl_xor(gd[mf][e], d);
        hb[mf][e] += __shfl_xor(hb[mf][e], d);
      }
  // row-stat reduce over lg (lanes lr, lr+16, lr+32, lr+48)
  if (wc == 0) {
#pragma unroll
    for (int mf = 0; mf < 4; ++mf) {
      sx[mf] += __shfl_xor(sx[mf], 16);
      sx[mf] += __shfl_xor(sx[mf], 32);
      sxx[mf] += __shfl_xor(sxx[mf], 16);
      sxx[mf] += __shfl_xor(sxx[mf], 32);
    }
  }

  if (tid < 256) { red[tid] = 0.f; red[256 + tid] = 0.f; }
  __syncthreads();
  if (lr == 0) {
#pragma unroll
    for (int mf = 0; mf < 4; ++mf)
#pragma unroll
      for (int e = 0; e < 4; ++e) {
        int row = wr * 64 + mf * 16 + lg * 4 + e;
        atomicAdd(&red[row], gd[mf][e]);
        atomicAdd(&red[128 + row], hb[mf][e]);
      }
  }
  if (wc == 0 && lg == 0) {
#pragma unroll
    for (int mf = 0; mf < 4; ++mf) {
      int row = wr * 64 + mf * 16 + lr;
      red[256 + row] = sx[mf];
      red[384 + row] = sxx[mf];
    }
  }
  // store clipped v (bf16)
#pragma unroll
  for (int mf = 0; mf < 4; ++mf)
#pragma unroll
    for (int nf = 0; nf < 4; ++nf)
#pragma unroll
      for (int e = 0; e < 4; ++e) {
        int row = wr * 64 + mf * 16 + lg * 4 + e;
        int col = wc * 64 + nf * 16 + lr;
        v_out[(r0 + row) * 256 + col] = f2b(accv[mf][nf][e]);
      }
  __syncthreads();

  // homeostatic MLP: one thread per row (threads 0..127)
  float c0v = 0.f, c2v = 0.f;
  if (tid < 128) {
    int row = tid;
    float mean = red[256 + row] * (1.f / 256.f);
    float var = red[384 + row] * (1.f / 256.f) - mean * mean;
    float st[4];
    st[0] = fabsf(var - 0.5f);               // surprise
    st[1] = red[128 + row] * (1.f / 256.f);  // excitation
    st[2] = sqrtf(scal[0]);                  // fatigue = |W|_F
    st[3] = 0.5f;                            // coherence
    float z[16];
#pragma unroll
    for (int o = 0; o < 16; ++o) {
      float a = s1b[o];
#pragma unroll
      for (int i = 0; i < 4; ++i) a += s1w[o * 4 + i] * st[i];
      z[o] = a;
    }
    float mu = 0.f;
#pragma unroll
    for (int o = 0; o < 16; ++o) mu += z[o];
    mu *= (1.f / 16.f);
    float vz = 0.f;
#pragma unroll
    for (int o = 0; o < 16; ++o) { float d2 = z[o] - mu; vz += d2 * d2; }
    vz *= (1.f / 16.f);
    float rs = rsqrtf(vz + 1e-5f);
#pragma unroll
    for (int o = 0; o < 16; ++o)
      z[o] = tanhf((z[o] - mu) * rs * lng[o] + lnb[o]);
    float z2[8];
#pragma unroll
    for (int o = 0; o < 8; ++o) {
      float a = s2b[o];
#pragma unroll
      for (int i = 0; i < 16; ++i) a += s2w[o * 16 + i] * z[i];
      z2[o] = fmaxf(a, 0.f);
    }
    float cc[2];
#pragma unroll
    for (int q = 0; q < 2; ++q) {
      int o = q * 2;  // controls[0] and controls[2]
      float a = ab[o];
#pragma unroll
      for (int i = 0; i < 8; ++i) a += aw[o * 8 + i] * z2[i];
      cc[q] = 1.f / (1.f + expf(-a));
    }
    c0v = cc[0]; c2v = cc[1];
    float graw = red[row] + gb[0];
    g_out[r0 + row] = 1.f / (1.f + expf(-graw));
  }
#pragma unroll
  for (int d = 1; d < 64; d <<= 1) {
    c0v += __shfl_xor(c0v, d);
    c2v += __shfl_xor(c2v, d);
  }
  if (lane == 0 && wid < 2) {
    atomicAdd(&scal[1], c0v);
    atomicAdd(&scal[2], c2v);
  }
}

// ---------------------------------------------------------------- k_hebb
// Split-K v^T x (K = 1024 rows per block) + fused output-0 write + col sum v^2.
__global__ __launch_bounds__(512, 2) void k_hebb(
    const float* __restrict__ x, const short* __restrict__ v_in,
    const float* __restrict__ g_sig, const float* __restrict__ scal,
    float* __restrict__ colv2, float* __restrict__ parts,
    float* __restrict__ out0) {
  __shared__ __align__(16) unsigned int ldsT[2 * 256 * 17];  // 34 KiB
  unsigned int* vT = ldsT;
  unsigned int* xT = ldsT + 256 * 17;
  int tid = threadIdx.x;
  int lane = tid & 63, wid = tid >> 6;
  int lr = lane & 15, lg = lane >> 4;
  int wr = wid >> 2, wc = wid & 3;
  size_t n0 = (size_t)blockIdx.x * 1024;
  float gv = scal[2] * (1.f / 262144.f);  // gate_value

  f32x4 acc[8][4] = {};
  float cv2[8] = {0.f, 0.f, 0.f, 0.f, 0.f, 0.f, 0.f, 0.f};
  int np = tid >> 5, ic = tid & 31, i0 = ic * 8;

  for (int nt = 0; nt < 32; ++nt) {
    size_t nr = n0 + nt * 32 + np * 2;
    s16x8 va = *(const s16x8*)(v_in + nr * 256 + i0);
    s16x8 vb = *(const s16x8*)(v_in + (nr + 1) * 256 + i0);
    f32x4 xa0 = *(const f32x4*)(x + nr * 256 + i0);
    f32x4 xa1 = *(const f32x4*)(x + nr * 256 + i0 + 4);
    f32x4 xb0 = *(const f32x4*)(x + (nr + 1) * 256 + i0);
    f32x4 xb1 = *(const f32x4*)(x + (nr + 1) * 256 + i0 + 4);
    float sa = g_sig[nr] * gv, sb = g_sig[nr + 1] * gv;
    f32x4 oa0, oa1, ob0, ob1;
#pragma unroll
    for (int j = 0; j < 4; ++j) {
      float fa = b2f(va[j]), fA = b2f(va[4 + j]);
      float fb = b2f(vb[j]), fB = b2f(vb[4 + j]);
      cv2[j] += fa * fa + fb * fb;
      cv2[4 + j] += fA * fA + fB * fB;
      oa0[j] = clip2(fa * sa); oa1[j] = clip2(fA * sa);
      ob0[j] = clip2(fb * sb); ob1[j] = clip2(fB * sb);
      vT[(i0 + j) * 17 + np] = packu(va[j], vb[j]);
      vT[(i0 + 4 + j) * 17 + np] = packu(va[4 + j], vb[4 + j]);
      xT[(i0 + j) * 17 + np] = packu(f2b(xa0[j]), f2b(xb0[j]));
      xT[(i0 + 4 + j) * 17 + np] = packu(f2b(xa1[j]), f2b(xb1[j]));
    }
    *(f32x4*)(out0 + nr * 256 + i0) = oa0;
    *(f32x4*)(out0 + nr * 256 + i0 + 4) = oa1;
    *(f32x4*)(out0 + (nr + 1) * 256 + i0) = ob0;
    *(f32x4*)(out0 + (nr + 1) * 256 + i0 + 4) = ob1;
    __syncthreads();
    int npb = lg * 4;
    s16x8 bfr[4];
#pragma unroll
    for (int nf = 0; nf < 4; ++nf) {
      int j = wc * 64 + nf * 16 + lr;
      u32x4 q;
      q[0] = xT[j * 17 + npb]; q[1] = xT[j * 17 + npb + 1];
      q[2] = xT[j * 17 + npb + 2]; q[3] = xT[j * 17 + npb + 3];
      bfr[nf] = __builtin_bit_cast(s16x8, q);
    }
#pragma unroll
    for (int mf = 0; mf < 8; ++mf) {
      int i = wr * 128 + mf * 16 + lr;
      u32x4 q;
      q[0] = vT[i * 17 + npb]; q[1] = vT[i * 17 + npb + 1];
      q[2] = vT[i * 17 + npb + 2]; q[3] = vT[i * 17 + npb + 3];
      s16x8 afr = __builtin_bit_cast(s16x8, q);
#pragma unroll
      for (int nf = 0; nf < 4; ++nf)
        acc[mf][nf] = mfma16(afr, bfr[nf], acc[mf][nf]);
    }
    __syncthreads();
  }
  float* myp = parts + (size_t)blockIdx.x * 65536;
#pragma unroll
  for (int mf = 0; mf < 8; ++mf)
#pragma unroll
    for (int nf = 0; nf < 4; ++nf)
#pragma unroll
      for (int e = 0; e < 4; ++e) {
        int i = wr * 128 + mf * 16 + lg * 4 + e;
        int j = wc * 64 + nf * 16 + lr;
        myp[i * 256 + j] = acc[mf][nf][e];
      }
  __syncthreads();
  float* cred = (float*)ldsT;
  if (tid < 256) cred[tid] = 0.f;
  __syncthreads();
#pragma unroll
  for (int j = 0; j < 8; ++j) atomicAdd(&cred[i0 + j], cv2[j]);
  __syncthreads();
  if (tid < 256) atomicAdd(&colv2[tid], cred[tid]);
}

// ---------------------------------------------------------------- k_mem1/2
__global__ __launch_bounds__(256) void k_mem1(
    const float* __restrict__ parts, const float* __restrict__ colv2,
    const float* __restrict__ sm, float* __restrict__ mem,
    float* __restrict__ scal) {
  int i = blockIdx.x, j = threadIdx.x;
  float hebb = 0.f;
#pragma unroll 8
  for (int p = 0; p < 256; ++p) hebb += parts[(size_t)p * 65536 + i * 256 + j];
  hebb *= (1.f / 262144.f);
  float mr = scal[1] * (1.f / 262144.f);  // metabolic_rate
  float smv = sm[i * 256 + j];
  float forget = colv2[i] * (1.f / 262144.f) * smv;
  float delta = tanhf(hebb - forget);
  float m = smv + delta * mr * 0.1f;
  mem[i * 256 + j] = m;
  float s = m * m;
#pragma unroll
  for (int d = 1; d < 64; d <<= 1) s += __shfl_xor(s, d);
  __shared__ float r4[4];
  if ((j & 63) == 0) r4[j >> 6] = s;
  __syncthreads();
  if (j == 0) atomicAdd(&scal[3], r4[0] + r4[1] + r4[2] + r4[3]);
}

__global__ __launch_bounds__(256) void k_mem2(const float* __restrict__ mem,
                                              const float* __restrict__ scal,
                                              float* __restrict__ out1) {
  int idx = blockIdx.x * 256 + threadIdx.x;
  float scale = 0.5f / fmaxf(sqrtf(scal[3]), 1e-6f);
  out1[idx] = mem[idx] * scale;
}

// ---------------------------------------------------------------- launch
extern "C" void kernel_launch(void* const* d_in, const int* in_sizes, int n_in,
                              void* d_out, int out_size, void* d_ws, size_t ws_size,
                              hipStream_t stream) {
  (void)in_sizes; (void)n_in; (void)out_size; (void)ws_size;
  const float* x   = (const float*)d_in[0];
  const float* Wm  = (const float*)d_in[1];
  const float* Vm  = (const float*)d_in[2];
  const float* gw  = (const float*)d_in[3];
  const float* gb  = (const float*)d_in[4];
  const float* s1w = (const float*)d_in[5];
  const float* s1b = (const float*)d_in[6];
  const float* lng = (const float*)d_in[7];
  const float* lnb = (const float*)d_in[8];
  const float* s2w = (const float*)d_in[9];
  const float* s2b = (const float*)d_in[10];
  const float* aw  = (const float*)d_in[11];
  const float* ab  = (const float*)d_in[12];
  const float* sm  = (const float*)d_in[13];
  float* out0 = (float*)d_out;
  float* out1 = out0 + (size_t)NTOK * 256;

  char* w = (char*)d_ws;
  short* v_ws  = (short*)w;                    // 134217728
  float* g_ws  = (float*)(w + 134217728);      // 1048576
  float* scal  = (float*)(w + 135266304);      // 256
  float* colv2 = (float*)(w + 135266560);      // 1024
  float* mem   = (float*)(w + 135267584);      // 262144
  float* parts = (float*)(w + 135529728);      // 67108864
  short* Vb    = (short*)(w + 202638592);      // 131072
  short* Wb    = (short*)(w + 202769664);      // 131072 (end ~202.9 MB)

  hipMemsetAsync(scal, 0, 1280, stream);       // scal[64] + colv2[256]
  k_prep<<<16, 1024, 0, stream>>>(Vm, Wm, Vb, Wb, scal);
  k_main<<<2048, 512, 0, stream>>>(x, Vb, Wb, gw, gb, s1w, s1b, lng, lnb,
                                   s2w, s2b, aw, ab, v_ws, g_ws, scal);
  k_hebb<<<256, 512, 0, stream>>>(x, v_ws, g_ws, scal, colv2, parts, out0);
  k_mem1<<<256, 256, 0, stream>>>(parts, colv2, sm, mem, scal);
  k_mem2<<<256, 256, 0, stream>>>(mem, scal, out1);
}

// Round 5
// 400.835 us; speedup vs baseline: 3.1613x; 1.2630x over previous
//
#include <hip/hip_runtime.h>
#include <hip/hip_bf16.h>

// MicroContinuumCell — MI355X. f32 I/O; bf16 MFMA internally.
// k_main: x staged cooperatively through LDS with 1-step register prefetch;
// Vb/Wb (256 KB, L2-resident) read directly from global in fragment layout.
// Workspace layout (~203 MB):
//   [0)            v bf16  [N][256]           134217728 B
//   [134217728)    sigmoid(gate_raw) f32 [N]    1048576 B
//   [135266304)    scal f32[64]: 0=|W|^2, 1=sum_c0, 2=sum_c2, 3=|mem|^2
//   [135266560)    colv2 f32[256]
//   [135267584)    mem f32[65536]
//   [135529728)    hebb partials f32[256][65536] 67108864 B
//   [202638592)    Vb bf16[65536]  131072 B
//   [202769664)    Wb bf16[65536]  131072 B

#define NTOK 262144

typedef short s16x4 __attribute__((ext_vector_type(4)));
typedef short s16x8 __attribute__((ext_vector_type(8)));
typedef float f32x4 __attribute__((ext_vector_type(4)));
typedef unsigned int u32x4 __attribute__((ext_vector_type(4)));
typedef __bf16 bf16x8 __attribute__((ext_vector_type(8)));

static __device__ __forceinline__ float b2f(short s) {
  unsigned int u = ((unsigned int)(unsigned short)s) << 16;
  return __builtin_bit_cast(float, u);
}
static __device__ __forceinline__ short f2b(float f) {
  __hip_bfloat16 h = __float2bfloat16(f);
  return (short)__builtin_bit_cast(unsigned short, h);
}
static __device__ __forceinline__ float clip2(float f) {
  return fminf(2.f, fmaxf(-2.f, f));
}
static __device__ __forceinline__ unsigned int packu(short lo, short hi) {
  return (unsigned int)(unsigned short)lo | ((unsigned int)(unsigned short)hi << 16);
}
static __device__ __forceinline__ f32x4 mfma16(s16x8 a, s16x8 b, f32x4 c) {
  return __builtin_amdgcn_mfma_f32_16x16x32_bf16(
      __builtin_bit_cast(bf16x8, a), __builtin_bit_cast(bf16x8, b), c, 0, 0, 0);
}

// ---------------------------------------------------------------- k_prep
__global__ __launch_bounds__(1024) void k_prep(const float* __restrict__ V,
                                               const float* __restrict__ W,
                                               short* __restrict__ Vb,
                                               short* __restrict__ Wb,
                                               float* __restrict__ scal) {
  int t = blockIdx.x * 1024 + threadIdx.x;  // 16384 threads, 4 elems each
  f32x4 v4 = *(const f32x4*)(V + (size_t)t * 4);
  f32x4 w4 = *(const f32x4*)(W + (size_t)t * 4);
  s16x4 vb, wb;
  float s = 0.f;
#pragma unroll
  for (int e = 0; e < 4; ++e) {
    vb[e] = f2b(v4[e]);
    wb[e] = f2b(w4[e]);
    s += w4[e] * w4[e];
  }
  *(s16x4*)(Vb + (size_t)t * 4) = vb;
  *(s16x4*)(Wb + (size_t)t * 4) = wb;
#pragma unroll
  for (int d = 1; d < 64; d <<= 1) s += __shfl_xor(s, d);
  __shared__ float r[16];
  if ((threadIdx.x & 63) == 0) r[threadIdx.x >> 6] = s;
  __syncthreads();
  if (threadIdx.x == 0) {
    float tt = 0.f;
#pragma unroll
    for (int i = 0; i < 16; ++i) tt += r[i];
    atomicAdd(&scal[0], tt);
  }
}

// ---------------------------------------------------------------- k_main
// Per block: 64 rows of x, fused v = clip(x V^T) and h = x W^T.
// 4 waves (1 M x 4 N); each wave: 64-row x 64-col tiles of both products.
// BK=32. x: coalesced LDS staging + 1-step register prefetch.
// Vb/Wb: direct global fragment loads (L2-hot, no restaging).
__global__ __launch_bounds__(256, 2) void k_main(
    const float* __restrict__ x, const short* __restrict__ Vb,
    const short* __restrict__ Wb, const float* __restrict__ gw,
    const float* __restrict__ gb, const float* __restrict__ s1w,
    const float* __restrict__ s1b, const float* __restrict__ lng,
    const float* __restrict__ lnb, const float* __restrict__ s2w,
    const float* __restrict__ s2b, const float* __restrict__ aw,
    const float* __restrict__ ab, short* __restrict__ v_out,
    float* __restrict__ g_out, float* __restrict__ scal) {
  __shared__ __align__(16) short xs[64 * 40];  // 5 KiB
  __shared__ float red[256];  // [0..63]=gate dot,[64..127]=|h|,[128..191]=sx,[192..255]=sxx
  int tid = threadIdx.x;
  int lane = tid & 63, wc = tid >> 6;  // 4 N-waves
  int lr = lane & 15, lg = lane >> 4;
  size_t r0 = (size_t)blockIdx.x * 64;

  f32x4 accv[4][4] = {};
  f32x4 acch[4][4] = {};
  float sx = 0.f, sxx = 0.f;
  int srow = tid >> 2, skc = tid & 3;  // staging: row 0..63, 8-col chunk

  const short* vbase = Vb + (size_t)(wc * 64 + lr) * 256 + lg * 8;
  const short* wbase = Wb + (size_t)(wc * 64 + lr) * 256 + lg * 8;
  const float* xsrc = x + (r0 + srow) * 256 + skc * 8;

  f32x4 rxa, rxb;  // x prefetch registers
  rxa = *(const f32x4*)(xsrc);
  rxb = *(const f32x4*)(xsrc + 4);

  for (int ks = 0; ks < 8; ++ks) {
    // ---- convert + stats + LDS write of current x chunk
    {
      s16x8 c;
#pragma unroll
      for (int e = 0; e < 4; ++e) {
        float f0 = rxa[e], f1 = rxb[e];
        sx += f0 + f1;
        sxx += f0 * f0 + f1 * f1;
        c[e] = f2b(f0);
        c[4 + e] = f2b(f1);
      }
      *(s16x8*)(xs + srow * 40 + skc * 8) = c;
    }
    __syncthreads();
    // ---- issue next K-step's x loads (latency hides under B+MFMA)
    if (ks < 7) {
      const float* src = xsrc + (ks + 1) * 32;
      rxa = *(const f32x4*)(src);
      rxb = *(const f32x4*)(src + 4);
    }
    // ---- B fragments straight from global (L2-hot)
    int k0 = ks * 32;
    s16x8 bv[4], bw[4];
#pragma unroll
    for (int nf = 0; nf < 4; ++nf) {
      bv[nf] = *(const s16x8*)(vbase + nf * 16 * 256 + k0);
      bw[nf] = *(const s16x8*)(wbase + nf * 16 * 256 + k0);
    }
    // ---- A fragments from LDS + MFMA
#pragma unroll
    for (int mf = 0; mf < 4; ++mf) {
      s16x8 a = *(const s16x8*)(xs + (mf * 16 + lr) * 40 + lg * 8);
#pragma unroll
      for (int nf = 0; nf < 4; ++nf) {
        accv[mf][nf] = mfma16(a, bv[nf], accv[mf][nf]);
        acch[mf][nf] = mfma16(a, bw[nf], acch[mf][nf]);
      }
    }
    __syncthreads();
  }

  // clip v; per-lane partials: gate dot and sum|h| per output row
  float gw4[4];
#pragma unroll
  for (int nf = 0; nf < 4; ++nf) gw4[nf] = gw[wc * 64 + nf * 16 + lr];
  float gd[4][4], hb[4][4];
#pragma unroll
  for (int mf = 0; mf < 4; ++mf)
#pragma unroll
    for (int e = 0; e < 4; ++e) { gd[mf][e] = 0.f; hb[mf][e] = 0.f; }
#pragma unroll
  for (int mf = 0; mf < 4; ++mf)
#pragma unroll
    for (int nf = 0; nf < 4; ++nf)
#pragma unroll
      for (int e = 0; e < 4; ++e) {
        float v = clip2(accv[mf][nf][e]);
        accv[mf][nf][e] = v;
        gd[mf][e] += v * gw4[nf];
        hb[mf][e] += fabsf(acch[mf][nf][e]);
      }
  // butterfly over the 16-col lane group (C/D: col = lane&15)
#pragma unroll
  for (int d = 1; d < 16; d <<= 1)
#pragma unroll
    for (int mf = 0; mf < 4; ++mf)
#pragma unroll
      for (int e = 0; e < 4; ++e) {
        gd[mf][e] += __shfl_xor(gd[mf][e], d);
        hb[mf][e] += __shfl_xor(hb[mf][e], d);
      }
  // row-stat reduce over the 4 threads sharing a staging row
  sx += __shfl_xor(sx, 1); sx += __shfl_xor(sx, 2);
  sxx += __shfl_xor(sxx, 1); sxx += __shfl_xor(sxx, 2);

  if (tid < 128) { red[tid] = 0.f; }
  __syncthreads();
  if (lr == 0) {
#pragma unroll
    for (int mf = 0; mf < 4; ++mf)
#pragma unroll
      for (int e = 0; e < 4; ++e) {
        int row = mf * 16 + lg * 4 + e;
        atomicAdd(&red[row], gd[mf][e]);
        atomicAdd(&red[64 + row], hb[mf][e]);
      }
  }
  if (skc == 0) { red[128 + srow] = sx; red[192 + srow] = sxx; }
  // store clipped v (bf16)
#pragma unroll
  for (int mf = 0; mf < 4; ++mf)
#pragma unroll
    for (int nf = 0; nf < 4; ++nf)
#pragma unroll
      for (int e = 0; e < 4; ++e) {
        int row = mf * 16 + lg * 4 + e;
        int col = wc * 64 + nf * 16 + lr;
        v_out[(r0 + row) * 256 + col] = f2b(accv[mf][nf][e]);
      }
  __syncthreads();

  // homeostatic MLP: one thread per row (threads 0..63 = wave 0)
  float c0v = 0.f, c2v = 0.f;
  if (tid < 64) {
    int row = tid;
    float mean = red[128 + row] * (1.f / 256.f);
    float var = red[192 + row] * (1.f / 256.f) - mean * mean;
    float st[4];
    st[0] = fabsf(var - 0.5f);              // surprise
    st[1] = red[64 + row] * (1.f / 256.f);  // excitation
    st[2] = sqrtf(scal[0]);                 // fatigue = |W|_F
    st[3] = 0.5f;                           // coherence
    float z[16];
#pragma unroll
    for (int o = 0; o < 16; ++o) {
      float a = s1b[o];
#pragma unroll
      for (int i = 0; i < 4; ++i) a += s1w[o * 4 + i] * st[i];
      z[o] = a;
    }
    float mu = 0.f;
#pragma unroll
    for (int o = 0; o < 16; ++o) mu += z[o];
    mu *= (1.f / 16.f);
    float vz = 0.f;
#pragma unroll
    for (int o = 0; o < 16; ++o) { float d2 = z[o] - mu; vz += d2 * d2; }
    vz *= (1.f / 16.f);
    float rs = rsqrtf(vz + 1e-5f);
#pragma unroll
    for (int o = 0; o < 16; ++o)
      z[o] = tanhf((z[o] - mu) * rs * lng[o] + lnb[o]);
    float z2[8];
#pragma unroll
    for (int o = 0; o < 8; ++o) {
      float a = s2b[o];
#pragma unroll
      for (int i = 0; i < 16; ++i) a += s2w[o * 16 + i] * z[i];
      z2[o] = fmaxf(a, 0.f);
    }
    float cc[2];
#pragma unroll
    for (int q = 0; q < 2; ++q) {
      int o = q * 2;  // controls[0] and controls[2]
      float a = ab[o];
#pragma unroll
      for (int i = 0; i < 8; ++i) a += aw[o * 8 + i] * z2[i];
      cc[q] = 1.f / (1.f + expf(-a));
    }
    c0v = cc[0]; c2v = cc[1];
    float graw = red[row] + gb[0];
    g_out[r0 + row] = 1.f / (1.f + expf(-graw));
  }
#pragma unroll
  for (int d = 1; d < 64; d <<= 1) {
    c0v += __shfl_xor(c0v, d);
    c2v += __shfl_xor(c2v, d);
  }
  if (tid == 0) {
    atomicAdd(&scal[1], c0v);
    atomicAdd(&scal[2], c2v);
  }
}

// ---------------------------------------------------------------- k_hebb
// Split-K v^T x (K = 1024 rows per block) + fused output-0 write + col sum v^2.
__global__ __launch_bounds__(512, 2) void k_hebb(
    const float* __restrict__ x, const short* __restrict__ v_in,
    const float* __restrict__ g_sig, const float* __restrict__ scal,
    float* __restrict__ colv2, float* __restrict__ parts,
    float* __restrict__ out0) {
  __shared__ __align__(16) unsigned int ldsT[2 * 256 * 17];  // 34 KiB
  unsigned int* vT = ldsT;
  unsigned int* xT = ldsT + 256 * 17;
  int tid = threadIdx.x;
  int lane = tid & 63, wid = tid >> 6;
  int lr = lane & 15, lg = lane >> 4;
  int wr = wid >> 2, wc = wid & 3;
  size_t n0 = (size_t)blockIdx.x * 1024;
  float gv = scal[2] * (1.f / 262144.f);  // gate_value

  f32x4 acc[8][4] = {};
  float cv2[8] = {0.f, 0.f, 0.f, 0.f, 0.f, 0.f, 0.f, 0.f};
  int np = tid >> 5, ic = tid & 31, i0 = ic * 8;

  for (int nt = 0; nt < 32; ++nt) {
    size_t nr = n0 + nt * 32 + np * 2;
    s16x8 va = *(const s16x8*)(v_in + nr * 256 + i0);
    s16x8 vb = *(const s16x8*)(v_in + (nr + 1) * 256 + i0);
    f32x4 xa0 = *(const f32x4*)(x + nr * 256 + i0);
    f32x4 xa1 = *(const f32x4*)(x + nr * 256 + i0 + 4);
    f32x4 xb0 = *(const f32x4*)(x + (nr + 1) * 256 + i0);
    f32x4 xb1 = *(const f32x4*)(x + (nr + 1) * 256 + i0 + 4);
    float sa = g_sig[nr] * gv, sb = g_sig[nr + 1] * gv;
    f32x4 oa0, oa1, ob0, ob1;
#pragma unroll
    for (int j = 0; j < 4; ++j) {
      float fa = b2f(va[j]), fA = b2f(va[4 + j]);
      float fb = b2f(vb[j]), fB = b2f(vb[4 + j]);
      cv2[j] += fa * fa + fb * fb;
      cv2[4 + j] += fA * fA + fB * fB;
      oa0[j] = clip2(fa * sa); oa1[j] = clip2(fA * sa);
      ob0[j] = clip2(fb * sb); ob1[j] = clip2(fB * sb);
      vT[(i0 + j) * 17 + np] = packu(va[j], vb[j]);
      vT[(i0 + 4 + j) * 17 + np] = packu(va[4 + j], vb[4 + j]);
      xT[(i0 + j) * 17 + np] = packu(f2b(xa0[j]), f2b(xb0[j]));
      xT[(i0 + 4 + j) * 17 + np] = packu(f2b(xa1[j]), f2b(xb1[j]));
    }
    *(f32x4*)(out0 + nr * 256 + i0) = oa0;
    *(f32x4*)(out0 + nr * 256 + i0 + 4) = oa1;
    *(f32x4*)(out0 + (nr + 1) * 256 + i0) = ob0;
    *(f32x4*)(out0 + (nr + 1) * 256 + i0 + 4) = ob1;
    __syncthreads();
    int npb = lg * 4;
    s16x8 bfr[4];
#pragma unroll
    for (int nf = 0; nf < 4; ++nf) {
      int j = wc * 64 + nf * 16 + lr;
      u32x4 q;
      q[0] = xT[j * 17 + npb]; q[1] = xT[j * 17 + npb + 1];
      q[2] = xT[j * 17 + npb + 2]; q[3] = xT[j * 17 + npb + 3];
      bfr[nf] = __builtin_bit_cast(s16x8, q);
    }
#pragma unroll
    for (int mf = 0; mf < 8; ++mf) {
      int i = wr * 128 + mf * 16 + lr;
      u32x4 q;
      q[0] = vT[i * 17 + npb]; q[1] = vT[i * 17 + npb + 1];
      q[2] = vT[i * 17 + npb + 2]; q[3] = vT[i * 17 + npb + 3];
      s16x8 afr = __builtin_bit_cast(s16x8, q);
#pragma unroll
      for (int nf = 0; nf < 4; ++nf)
        acc[mf][nf] = mfma16(afr, bfr[nf], acc[mf][nf]);
    }
    __syncthreads();
  }
  float* myp = parts + (size_t)blockIdx.x * 65536;
#pragma unroll
  for (int mf = 0; mf < 8; ++mf)
#pragma unroll
    for (int nf = 0; nf < 4; ++nf)
#pragma unroll
      for (int e = 0; e < 4; ++e) {
        int i = wr * 128 + mf * 16 + lg * 4 + e;
        int j = wc * 64 + nf * 16 + lr;
        myp[i * 256 + j] = acc[mf][nf][e];
      }
  __syncthreads();
  float* cred = (float*)ldsT;
  if (tid < 256) cred[tid] = 0.f;
  __syncthreads();
#pragma unroll
  for (int j = 0; j < 8; ++j) atomicAdd(&cred[i0 + j], cv2[j]);
  __syncthreads();
  if (tid < 256) atomicAdd(&colv2[tid], cred[tid]);
}

// ---------------------------------------------------------------- k_mem1/2
__global__ __launch_bounds__(256) void k_mem1(
    const float* __restrict__ parts, const float* __restrict__ colv2,
    const float* __restrict__ sm, float* __restrict__ mem,
    float* __restrict__ scal) {
  int i = blockIdx.x, j = threadIdx.x;
  float hebb = 0.f;
#pragma unroll 8
  for (int p = 0; p < 256; ++p) hebb += parts[(size_t)p * 65536 + i * 256 + j];
  hebb *= (1.f / 262144.f);
  float mr = scal[1] * (1.f / 262144.f);  // metabolic_rate
  float smv = sm[i * 256 + j];
  float forget = colv2[i] * (1.f / 262144.f) * smv;
  float delta = tanhf(hebb - forget);
  float m = smv + delta * mr * 0.1f;
  mem[i * 256 + j] = m;
  float s = m * m;
#pragma unroll
  for (int d = 1; d < 64; d <<= 1) s += __shfl_xor(s, d);
  __shared__ float r4[4];
  if ((j & 63) == 0) r4[j >> 6] = s;
  __syncthreads();
  if (j == 0) atomicAdd(&scal[3], r4[0] + r4[1] + r4[2] + r4[3]);
}

__global__ __launch_bounds__(256) void k_mem2(const float* __restrict__ mem,
                                              const float* __restrict__ scal,
                                              float* __restrict__ out1) {
  int idx = blockIdx.x * 256 + threadIdx.x;
  float scale = 0.5f / fmaxf(sqrtf(scal[3]), 1e-6f);
  out1[idx] = mem[idx] * scale;
}

// ---------------------------------------------------------------- launch
extern "C" void kernel_launch(void* const* d_in, const int* in_sizes, int n_in,
                              void* d_out, int out_size, void* d_ws, size_t ws_size,
                              hipStream_t stream) {
  (void)in_sizes; (void)n_in; (void)out_size; (void)ws_size;
  const float* x   = (const float*)d_in[0];
  const float* Wm  = (const float*)d_in[1];
  const float* Vm  = (const float*)d_in[2];
  const float* gw  = (const float*)d_in[3];
  const float* gb  = (const float*)d_in[4];
  const float* s1w = (const float*)d_in[5];
  const float* s1b = (const float*)d_in[6];
  const float* lng = (const float*)d_in[7];
  const float* lnb = (const float*)d_in[8];
  const float* s2w = (const float*)d_in[9];
  const float* s2b = (const float*)d_in[10];
  const float* aw  = (const float*)d_in[11];
  const float* ab  = (const float*)d_in[12];
  const float* sm  = (const float*)d_in[13];
  float* out0 = (float*)d_out;
  float* out1 = out0 + (size_t)NTOK * 256;

  char* w = (char*)d_ws;
  short* v_ws  = (short*)w;                    // 134217728
  float* g_ws  = (float*)(w + 134217728);      // 1048576
  float* scal  = (float*)(w + 135266304);      // 256
  float* colv2 = (float*)(w + 135266560);      // 1024
  float* mem   = (float*)(w + 135267584);      // 262144
  float* parts = (float*)(w + 135529728);      // 67108864
  short* Vb    = (short*)(w + 202638592);      // 131072
  short* Wb    = (short*)(w + 202769664);      // 131072 (end ~202.9 MB)

  hipMemsetAsync(scal, 0, 1280, stream);       // scal[64] + colv2[256]
  k_prep<<<16, 1024, 0, stream>>>(Vm, Wm, Vb, Wb, scal);
  k_main<<<4096, 256, 0, stream>>>(x, Vb, Wb, gw, gb, s1w, s1b, lng, lnb,
                                   s2w, s2b, aw, ab, v_ws, g_ws, scal);
  k_hebb<<<256, 512, 0, stream>>>(x, v_ws, g_ws, scal, colv2, parts, out0);
  k_mem1<<<256, 256, 0, stream>>>(parts, colv2, sm, mem, scal);
  k_mem2<<<256, 256, 0, stream>>>(mem, scal, out1);
}